// Round 2
// baseline (467.051 us; speedup 1.0000x reference)
//
#include <hip/hip_runtime.h>

// t-product forward: out = relu(bcirc(W) @ X + B)
// X: [784][65536] fp32, A = bcirc(W): [784][784], out: [784][65536] fp32.
// R2: pre-convert X to bf16 in d_ws, tiled in the GEMM's exact LDS staging
// order -> hot loop stages A and X with linear global_load_lds (no VALU
// conversion, no ds_write, no bank conflicts). Fallback to R1 fused kernel
// if ws_size < 106 MB.

typedef __attribute__((ext_vector_type(4))) float f32x4;
typedef __attribute__((ext_vector_type(8))) short s16x8;
typedef __attribute__((ext_vector_type(4))) unsigned int u32x4;

#define BATCH    65536
#define MROWS    784
#define KDIM     784
#define KSTEPS   25            // K padded to 800, BK=32
#define BM       112           // 7 x 16; 784/112 = 7 exact
#define BN       256
#define MT       7
#define NT       256
#define NWG      (MT*NT)       // 1792 (divisible by 8 -> bijective XCD swizzle)
#define ATILE_ELEMS 3584       // [kb=4][m=112][e=8] bf16 per (mt,ks) tile
#define AWS_ELEMS  (MT*KSTEPS*ATILE_ELEMS)       // 627200 elems
#define XTILE_ELEMS 8192       // [kb=4][n=256][e=8] bf16 per (nt,ks) tile = 16 KB
#define XWS_ELEMS  ((size_t)NT*KSTEPS*XTILE_ELEMS) // 52,428,800 elems
#define WS_NEED    ((AWS_ELEMS + XWS_ELEMS) * 2)   // ~106.1 MB

// round-to-nearest-even f32 -> bf16 (bias-free over 784-term dot products)
__device__ __forceinline__ unsigned int rne1(float f) {
  unsigned int u = __float_as_uint(f);
  return (u + 0x7fffu + ((u >> 16) & 1u)) >> 16;
}
__device__ __forceinline__ unsigned int pack2(float a, float b) {
  return rne1(a) | (rne1(b) << 16);
}

typedef const __attribute__((address_space(1))) unsigned int glb_uint;
typedef __attribute__((address_space(3))) unsigned int lds_uint;
__device__ __forceinline__ void async16(const void* g, void* l) {
  __builtin_amdgcn_global_load_lds((glb_uint*)g, (lds_uint*)l, 16, 0, 0);
}

// ---- prep: A = bcirc(W) as bf16, pre-tiled in LDS staging order ----
__global__ void build_A(const float* __restrict__ W, unsigned short* __restrict__ A_ws) {
  int idx = blockIdx.x * 256 + threadIdx.x;
  if (idx >= AWS_ELEMS) return;
  int tile = idx / ATILE_ELEMS;
  int o    = idx - tile * ATILE_ELEMS;
  int mt   = tile / KSTEPS;
  int ks   = tile - mt * KSTEPS;
  int e    = o & 7;
  int slot = o >> 3;
  int kb   = slot / BM;
  int ml   = slot - kb * BM;
  int r    = mt * BM + ml;
  int c    = ks * 32 + kb * 8 + e;
  float v = 0.0f;
  if (c < KDIM) {
    int kl = r / 28, mm = r - kl * 28;
    int j  = c / 28, n  = c - j * 28;
    int d = kl - j; if (d < 0) d += 28;
    v = W[(d * 28 + mm) * 28 + n];
  }
  A_ws[idx] = (unsigned short)rne1(v);
}

// ---- prep: X fp32 -> bf16, layout [nt][ks][kb][n][e]; one 16B slot/thread ----
__global__ void convert_x(const float* __restrict__ X, unsigned short* __restrict__ Xw) {
  int gid = blockIdx.x * 256 + threadIdx.x;   // < 6,553,600 slots
  int tile   = gid >> 10;                     // nt*25 + ks
  int within = gid & 1023;
  int kb = within >> 8, n = within & 255;
  int nt = tile / KSTEPS, ks = tile - nt * KSTEPS;
  int k0 = ks * 32 + kb * 8;
  const float* src = X + (size_t)k0 * BATCH + nt * BN + n;
  float v[8];
  if (k0 + 7 < KDIM) {
#pragma unroll
    for (int e = 0; e < 8; ++e) v[e] = src[(size_t)e << 16];
  } else {
#pragma unroll
    for (int e = 0; e < 8; ++e) v[e] = (k0 + e < KDIM) ? src[(size_t)e << 16] : 0.0f;
  }
  u32x4 w;
  w.x = pack2(v[0], v[1]);
  w.y = pack2(v[2], v[3]);
  w.z = pack2(v[4], v[5]);
  w.w = pack2(v[6], v[7]);
  *(u32x4*)(Xw + ((size_t)gid << 3)) = w;
}

// ---- main GEMM: all-bf16 inputs, both operands via linear global_load_lds ----
__global__ __launch_bounds__(256, 2) void tnn_gemm2(
    const unsigned short* __restrict__ A_ws, const unsigned short* __restrict__ X_ws,
    const float* __restrict__ Bias, float* __restrict__ C) {
  __shared__ __align__(16) unsigned short a_lds[ATILE_ELEMS];   // 7168 B
  __shared__ __align__(16) unsigned short x_lds[XTILE_ELEMS];   // 16384 B

  int bid = blockIdx.x;
  int wg  = (bid & 7) * (NWG / 8) + (bid >> 3);   // XCD-aware, bijective
  int nt  = wg / MT;
  int mt  = wg - nt * MT;

  int tid  = threadIdx.x;
  int lane = tid & 63;
  int wave = tid >> 6;

  f32x4 acc[7][4];
#pragma unroll
  for (int i = 0; i < 7; ++i)
#pragma unroll
    for (int j = 0; j < 4; ++j)
      acc[i][j] = (f32x4){0.f, 0.f, 0.f, 0.f};

  // fragment read addressing (16-lane groups read 256B-contiguous runs;
  // group strides 1792B / 4096B are 128B-aligned -> conflict-free)
  int a_rd    = (((lane >> 4) * BM) + (lane & 15)) * 16;          // + i*256
  int x_rd    = ((lane >> 4) * 256 + wave * 64 + (lane & 15)) * 16; // + jn*256

  const unsigned short* abase = A_ws + (size_t)mt * KSTEPS * ATILE_ELEMS;
  const unsigned short* xbase = X_ws + (size_t)nt * KSTEPS * XTILE_ELEMS;

  for (int ks = 0; ks < KSTEPS; ++ks) {
    __syncthreads();   // prev step's ds_reads done -> safe to overwrite LDS

    // stage A: 7 KB = 7 x 1KB chunks across 4 waves
    const unsigned short* at = abase + ks * ATILE_ELEMS;
    async16(at + wave * 512 + lane * 8, &a_lds[wave * 512]);
    if (wave < 3)
      async16(at + (wave + 4) * 512 + lane * 8, &a_lds[(wave + 4) * 512]);

    // stage X: 16 KB = 4 x 1KB per wave
    const unsigned short* xt = xbase + ks * XTILE_ELEMS;
#pragma unroll
    for (int c = 0; c < 4; ++c)
      async16(xt + wave * 2048 + c * 512 + lane * 8,
              &x_lds[wave * 2048 + c * 512]);

    __syncthreads();   // staging drained (compiler emits vmcnt(0))

    s16x8 af[7], xf[4];
#pragma unroll
    for (int i = 0; i < 7; ++i)
      af[i] = *(const s16x8*)((const char*)a_lds + a_rd + i * 256);
#pragma unroll
    for (int jn = 0; jn < 4; ++jn)
      xf[jn] = *(const s16x8*)((const char*)x_lds + x_rd + jn * 256);
#pragma unroll
    for (int i = 0; i < 7; ++i)
#pragma unroll
      for (int jn = 0; jn < 4; ++jn)
        acc[i][jn] = __builtin_amdgcn_mfma_f32_16x16x32_bf16(af[i], xf[jn], acc[i][jn], 0, 0, 0);
  }

  int colbase = nt * BN + wave * 64 + (lane & 15);
#pragma unroll
  for (int i = 0; i < 7; ++i) {
    int r0 = mt * BM + i * 16 + ((lane >> 4) << 2);
    f32x4 bv = *(const f32x4*)&Bias[r0];
#pragma unroll
    for (int jn = 0; jn < 4; ++jn) {
      size_t cb = ((size_t)r0 << 16) + (size_t)(colbase + jn * 16);
#pragma unroll
      for (int d = 0; d < 4; ++d) {
        float vv = acc[i][jn][d] + bv[d];
        C[cb + ((size_t)d << 16)] = fmaxf(vv, 0.0f);
      }
    }
  }
}

// ---------------- fallback (R1, proven): fused conversion ----------------
__global__ __launch_bounds__(256, 2) void tnn_gemm(
    const float* __restrict__ X, const unsigned short* __restrict__ A_ws,
    const float* __restrict__ Bias, float* __restrict__ C) {
  __shared__ __align__(16) unsigned short a_lds[ATILE_ELEMS];
  __shared__ __align__(16) unsigned short x_lds[8192];

  int bid = blockIdx.x;
  int wg  = (bid & 7) * (NWG / 8) + (bid >> 3);
  int nt  = wg / MT;
  int mt  = wg - nt * MT;
  int tid  = threadIdx.x;
  int lane = tid & 63;
  int wave = tid >> 6;

  f32x4 acc[7][4];
#pragma unroll
  for (int i = 0; i < 7; ++i)
#pragma unroll
    for (int j = 0; j < 4; ++j)
      acc[i][j] = (f32x4){0.f, 0.f, 0.f, 0.f};

  const float* xbase = X + (size_t)(nt * BN) + ((size_t)(wave * 8) << 16) + (lane << 2);
  int wslot0 = wave * 256 + (lane << 2);
  int a_rd    = (((lane >> 4) * BM) + (lane & 15)) * 16;
  int x_slot0 = (lane >> 4) * 256 + wave * 64 + (lane & 15);

  for (int ks = 0; ks < KSTEPS; ++ks) {
    f32x4 v[8];
    int k0 = ks * 32 + wave * 8;
    const float* xs = xbase + ((size_t)ks << 21);
#pragma unroll
    for (int dk = 0; dk < 8; ++dk) {
      if (k0 + dk < KDIM) v[dk] = *(const f32x4*)(xs + ((size_t)dk << 16));
      else                v[dk] = (f32x4){0.f, 0.f, 0.f, 0.f};
    }
    __syncthreads();
    const unsigned short* atile = A_ws + (size_t)(mt * KSTEPS + ks) * ATILE_ELEMS;
    async16(atile + wave * 512 + lane * 8, &a_lds[wave * 512]);
    if (wave < 3)
      async16(atile + (wave + 4) * 512 + lane * 8, &a_lds[(wave + 4) * 512]);
#pragma unroll
    for (int di = 0; di < 4; ++di) {
      int slot = wslot0 + di;
      int boff = (slot * 16) ^ (((slot >> 5) & 7) << 4);
      u32x4 w;
      w.x = pack2(v[0][di], v[1][di]);
      w.y = pack2(v[2][di], v[3][di]);
      w.z = pack2(v[4][di], v[5][di]);
      w.w = pack2(v[6][di], v[7][di]);
      *(u32x4*)((char*)x_lds + boff) = w;
    }
    __syncthreads();
    s16x8 af[7], xf[4];
#pragma unroll
    for (int i = 0; i < 7; ++i)
      af[i] = *(const s16x8*)((const char*)a_lds + a_rd + i * 256);
#pragma unroll
    for (int jn = 0; jn < 4; ++jn) {
      int slot = x_slot0 + jn * 16;
      int boff = (slot * 16) ^ (((slot >> 5) & 7) << 4);
      xf[jn] = *(const s16x8*)((const char*)x_lds + boff);
    }
#pragma unroll
    for (int i = 0; i < 7; ++i)
#pragma unroll
      for (int jn = 0; jn < 4; ++jn)
        acc[i][jn] = __builtin_amdgcn_mfma_f32_16x16x32_bf16(af[i], xf[jn], acc[i][jn], 0, 0, 0);
  }

  int colbase = nt * BN + wave * 64 + (lane & 15);
#pragma unroll
  for (int i = 0; i < 7; ++i) {
    int r0 = mt * BM + i * 16 + ((lane >> 4) << 2);
    f32x4 bv = *(const f32x4*)&Bias[r0];
#pragma unroll
    for (int jn = 0; jn < 4; ++jn) {
      size_t cb = ((size_t)r0 << 16) + (size_t)(colbase + jn * 16);
#pragma unroll
      for (int d = 0; d < 4; ++d) {
        float vv = acc[i][jn][d] + bv[d];
        C[cb + ((size_t)d << 16)] = fmaxf(vv, 0.0f);
      }
    }
  }
}

extern "C" void kernel_launch(void* const* d_in, const int* in_sizes, int n_in,
                              void* d_out, int out_size, void* d_ws, size_t ws_size,
                              hipStream_t stream) {
  const float* x  = (const float*)d_in[0];   // (28, 28, 65536) = [784][65536]
  const float* W  = (const float*)d_in[1];   // (28, 28, 28)
  const float* B  = (const float*)d_in[2];   // (28, 28, 1)
  float* out = (float*)d_out;
  unsigned short* A_ws = (unsigned short*)d_ws;
  unsigned short* X_ws = A_ws + AWS_ELEMS;

  build_A<<<(AWS_ELEMS + 255) / 256, 256, 0, stream>>>(W, A_ws);
  if (ws_size >= WS_NEED) {
    convert_x<<<(int)(XWS_ELEMS / 8 / 256), 256, 0, stream>>>(x, X_ws);
    tnn_gemm2<<<NWG, 256, 0, stream>>>(A_ws, X_ws, B, out);
  } else {
    tnn_gemm<<<NWG, 256, 0, stream>>>(x, A_ws, B, out);
  }
}

// Round 3
// 451.717 us; speedup vs baseline: 1.0339x; 1.0339x over previous
//
#include <hip/hip_runtime.h>

// t-product forward: out = relu(bcirc(W) @ X + B)
// X: [784][65536] fp32, A = bcirc(W): [784][784], out: [784][65536] fp32.
// R3: fused single-pass GEMM. X is loaded fp32->regs (issued before the
// barrier, T14), converted with v_cvt_pk_bf16_f32 (RNE, 2 vals/inst), and
// ds_written with a CORRECT xor-swizzle (slot bits 3-5 -> byte bits 4-6,
// 2-way max on both write and read = free). A = bcirc(W) is pre-tiled bf16
// in d_ws and staged with linear global_load_lds width-16.

typedef __attribute__((ext_vector_type(4))) float f32x4;
typedef __attribute__((ext_vector_type(8))) short s16x8;
typedef __attribute__((ext_vector_type(4))) unsigned int u32x4;

#define BATCH    65536
#define MROWS    784
#define KDIM     784
#define KSTEPS   25            // K padded to 800, BK=32
#define BM       112           // 7 x 16; 784/112 = 7 exact (divisors of 784 that are x16: 16, 112)
#define BN       256
#define MT       7
#define NT       256
#define NWG      (MT*NT)       // 1792 (divisible by 8 -> bijective XCD swizzle)
#define ATILE_ELEMS 3584       // [kb=4][m=112][e=8] bf16 per (mt,ks) tile
#define AWS_ELEMS  (MT*KSTEPS*ATILE_ELEMS)   // 627200 elems = 1.25 MB

// RNE f32->bf16 (prep kernel only; hot loop uses v_cvt_pk_bf16_f32)
__device__ __forceinline__ unsigned int rne1(float f) {
  unsigned int u = __float_as_uint(f);
  return (u + 0x7fffu + ((u >> 16) & 1u)) >> 16;
}

// HW packed cvt: D[15:0]=bf16(lo), D[31:16]=bf16(hi), RNE
__device__ __forceinline__ unsigned int cvtpk(float lo, float hi) {
  unsigned int r;
  asm("v_cvt_pk_bf16_f32 %0, %1, %2" : "=v"(r) : "v"(lo), "v"(hi));
  return r;
}

// xor-swizzle: 16B slot -> byte offset; involution applied on write AND read.
__device__ __forceinline__ int swz(int slot) {
  return (slot * 16) ^ (((slot >> 3) & 7) << 4);
}

typedef const __attribute__((address_space(1))) unsigned int glb_uint;
typedef __attribute__((address_space(3))) unsigned int lds_uint;
__device__ __forceinline__ void async16(const void* g, void* l) {
  __builtin_amdgcn_global_load_lds((glb_uint*)g, (lds_uint*)l, 16, 0, 0);
}

// ---- prep: A = bcirc(W) as bf16, pre-tiled in the GEMM's LDS staging order ----
__global__ void build_A(const float* __restrict__ W, unsigned short* __restrict__ A_ws) {
  int idx = blockIdx.x * 256 + threadIdx.x;
  if (idx >= AWS_ELEMS) return;
  int tile = idx / ATILE_ELEMS;
  int o    = idx - tile * ATILE_ELEMS;
  int mt   = tile / KSTEPS;
  int ks   = tile - mt * KSTEPS;
  int e    = o & 7;
  int slot = o >> 3;
  int kb   = slot / BM;
  int ml   = slot - kb * BM;
  int r    = mt * BM + ml;
  int c    = ks * 32 + kb * 8 + e;
  float v = 0.0f;
  if (c < KDIM) {
    int kl = r / 28, mm = r - kl * 28;
    int j  = c / 28, n  = c - j * 28;
    int d = kl - j; if (d < 0) d += 28;
    v = W[(d * 28 + mm) * 28 + n];
  }
  A_ws[idx] = (unsigned short)rne1(v);
}

// ---- fused GEMM: fp32 X -> cvt_pk -> swizzled LDS; A via global_load_lds ----
__global__ __launch_bounds__(256, 2) void tnn_fused(
    const float* __restrict__ X, const unsigned short* __restrict__ A_ws,
    const float* __restrict__ Bias, float* __restrict__ C) {
  __shared__ __align__(16) unsigned short a_lds[ATILE_ELEMS];   // 7168 B, linear
  __shared__ __align__(16) unsigned short x_lds[8192];          // 16384 B, swizzled

  int bid = blockIdx.x;
  int wg  = (bid & 7) * (NWG / 8) + (bid >> 3);   // XCD-aware, bijective
  int nt  = wg / MT;
  int mt  = wg - nt * MT;

  int tid  = threadIdx.x;
  int lane = tid & 63;
  int wave = tid >> 6;          // 4 waves; wave-tile 112 x 64

  f32x4 acc[7][4];
#pragma unroll
  for (int i = 0; i < 7; ++i)
#pragma unroll
    for (int j = 0; j < 4; ++j)
      acc[i][j] = (f32x4){0.f, 0.f, 0.f, 0.f};

  // X staging ownership: thread -> (kb = wave -> 8 k-rows, 4 cols at lane*4)
  const float* xbase = X + (size_t)(nt * BN) + ((size_t)(wave * 8) << 16) + (lane << 2);
  int wslot0 = wave * 256 + (lane << 2);

  // fragment read addressing
  int a_rd    = (((lane >> 4) * BM) + (lane & 15)) * 16;            // + i*256
  int x_slot0 = (lane >> 4) * 256 + wave * 64 + (lane & 15);        // + jn*16

  for (int ks = 0; ks < KSTEPS; ++ks) {
    // global X loads to regs: issued before the barrier, consumed after
    // (T14 async-split: HBM latency hides under prev MFMA + barrier)
    f32x4 v[8];
    int k0 = ks * 32 + wave * 8;
    const float* xs = xbase + ((size_t)ks << 21);
#pragma unroll
    for (int dk = 0; dk < 8; ++dk) {
      if (k0 + dk < KDIM) v[dk] = *(const f32x4*)(xs + ((size_t)dk << 16));
      else                v[dk] = (f32x4){0.f, 0.f, 0.f, 0.f};   // K zero-pad
    }

    __syncthreads();   // prev step's ds_reads done -> safe to overwrite LDS

    // stage A: 7 x 1KB async direct-to-LDS across 4 waves
    const unsigned short* atile = A_ws + (size_t)(mt * KSTEPS + ks) * ATILE_ELEMS;
    async16(atile + wave * 512 + lane * 8, &a_lds[wave * 512]);
    if (wave < 3)
      async16(atile + (wave + 4) * 512 + lane * 8, &a_lds[(wave + 4) * 512]);

    // stage X: cvt_pk + 8x4 transpose-pack + swizzled ds_write_b128
#pragma unroll
    for (int di = 0; di < 4; ++di) {
      u32x4 w;
      w.x = cvtpk(v[0][di], v[1][di]);
      w.y = cvtpk(v[2][di], v[3][di]);
      w.z = cvtpk(v[4][di], v[5][di]);
      w.w = cvtpk(v[6][di], v[7][di]);
      *(u32x4*)((char*)x_lds + swz(wslot0 + di)) = w;
    }

    __syncthreads();   // staging drained

    // compute: 7 A-frags + 4 B-frags -> 28 MFMAs
    s16x8 af[7], xf[4];
#pragma unroll
    for (int i = 0; i < 7; ++i)
      af[i] = *(const s16x8*)((const char*)a_lds + a_rd + i * 256);
#pragma unroll
    for (int jn = 0; jn < 4; ++jn)
      xf[jn] = *(const s16x8*)((const char*)x_lds + swz(x_slot0 + jn * 16));
#pragma unroll
    for (int i = 0; i < 7; ++i)
#pragma unroll
      for (int jn = 0; jn < 4; ++jn)
        acc[i][jn] = __builtin_amdgcn_mfma_f32_16x16x32_bf16(af[i], xf[jn], acc[i][jn], 0, 0, 0);
  }

  // epilogue: + bias, relu, store
  int colbase = nt * BN + wave * 64 + (lane & 15);
#pragma unroll
  for (int i = 0; i < 7; ++i) {
    int r0 = mt * BM + i * 16 + ((lane >> 4) << 2);   // D row = (lane>>4)*4 + d
    f32x4 bv = *(const f32x4*)&Bias[r0];
#pragma unroll
    for (int jn = 0; jn < 4; ++jn) {
      size_t cb = ((size_t)r0 << 16) + (size_t)(colbase + jn * 16);
#pragma unroll
      for (int d = 0; d < 4; ++d) {
        float vv = acc[i][jn][d] + bv[d];
        C[cb + ((size_t)d << 16)] = fmaxf(vv, 0.0f);
      }
    }
  }
}

extern "C" void kernel_launch(void* const* d_in, const int* in_sizes, int n_in,
                              void* d_out, int out_size, void* d_ws, size_t ws_size,
                              hipStream_t stream) {
  const float* x  = (const float*)d_in[0];   // (28, 28, 65536) = [784][65536]
  const float* W  = (const float*)d_in[1];   // (28, 28, 28)
  const float* B  = (const float*)d_in[2];   // (28, 28, 1)
  float* out = (float*)d_out;
  unsigned short* A_ws = (unsigned short*)d_ws;  // 1.25 MB bf16 bcirc(W)

  build_A<<<(AWS_ELEMS + 255) / 256, 256, 0, stream>>>(W, A_ws);
  tnn_fused<<<NWG, 256, 0, stream>>>(x, A_ws, B, out);
}

// Round 4
// 451.366 us; speedup vs baseline: 1.0347x; 1.0008x over previous
//
#include <hip/hip_runtime.h>

// t-product forward: out = relu(bcirc(W) @ X + B)
// X: [784][65536] fp32, A = bcirc(W): [784][784], out: [784][65536] fp32.
// R4: fused GEMM with double-buffered LDS + ONE barrier per K-step +
// pipelined register staging (T3 2-phase + T14): global loads for step
// ks+1 issue before the MFMA block of step ks, cvt_pk+swizzled ds_write
// land after it. A = bcirc(W) pre-tiled bf16 in d_ws, staged with linear
// global_load_lds width-16 into the alternate buffer.

typedef __attribute__((ext_vector_type(4))) float f32x4;
typedef __attribute__((ext_vector_type(8))) short s16x8;
typedef __attribute__((ext_vector_type(4))) unsigned int u32x4;

#define BATCH    65536
#define MROWS    784
#define KDIM     784
#define KSTEPS   25            // K padded to 800, BK=32
#define BM       112           // 7 x 16; 784/112 = 7 exact
#define BN       256
#define MT       7
#define NT       256
#define NWG      (MT*NT)       // 1792 (divisible by 8 -> bijective XCD swizzle)
#define ATILE_ELEMS 3584       // [kb=4][m=112][e=8] bf16 per (mt,ks) tile
#define AWS_ELEMS  (MT*KSTEPS*ATILE_ELEMS)   // 627200 elems = 1.25 MB

// RNE f32->bf16 (prep kernel only)
__device__ __forceinline__ unsigned int rne1(float f) {
  unsigned int u = __float_as_uint(f);
  return (u + 0x7fffu + ((u >> 16) & 1u)) >> 16;
}

// HW packed cvt: D[15:0]=bf16(lo), D[31:16]=bf16(hi), RNE
__device__ __forceinline__ unsigned int cvtpk(float lo, float hi) {
  unsigned int r;
  asm("v_cvt_pk_bf16_f32 %0, %1, %2" : "=v"(r) : "v"(lo), "v"(hi));
  return r;
}

// xor-swizzle: 16B slot -> byte offset; involution on write AND read.
// Write slots vary in bits 2-7 across a wave; read slots in bits 0-3 (+jn).
// XOR of slot bits 3-5 into byte bits 4-6 leaves both sides <=2-way (free).
__device__ __forceinline__ int swz(int slot) {
  return (slot * 16) ^ (((slot >> 3) & 7) << 4);
}

typedef const __attribute__((address_space(1))) unsigned int glb_uint;
typedef __attribute__((address_space(3))) unsigned int lds_uint;
__device__ __forceinline__ void async16(const void* g, void* l) {
  __builtin_amdgcn_global_load_lds((glb_uint*)g, (lds_uint*)l, 16, 0, 0);
}

// ---- prep: A = bcirc(W) as bf16, pre-tiled in the GEMM's LDS staging order ----
__global__ void build_A(const float* __restrict__ W, unsigned short* __restrict__ A_ws) {
  int idx = blockIdx.x * 256 + threadIdx.x;
  if (idx >= AWS_ELEMS) return;
  int tile = idx / ATILE_ELEMS;
  int o    = idx - tile * ATILE_ELEMS;
  int mt   = tile / KSTEPS;
  int ks   = tile - mt * KSTEPS;
  int e    = o & 7;
  int slot = o >> 3;
  int kb   = slot / BM;
  int ml   = slot - kb * BM;
  int r    = mt * BM + ml;
  int c    = ks * 32 + kb * 8 + e;
  float v = 0.0f;
  if (c < KDIM) {
    int kl = r / 28, mm = r - kl * 28;
    int j  = c / 28, n  = c - j * 28;
    int d = kl - j; if (d < 0) d += 28;
    v = W[(d * 28 + mm) * 28 + n];
  }
  A_ws[idx] = (unsigned short)rne1(v);
}

__global__ __launch_bounds__(256, 2) void tnn_fused(
    const float* __restrict__ X, const unsigned short* __restrict__ A_ws,
    const float* __restrict__ Bias, float* __restrict__ C) {
  // double-buffered: A linear (DMA dest), X swizzled (reg-staged)
  __shared__ __align__(16) unsigned short a_lds[2][ATILE_ELEMS];  // 2 x 7168 B
  __shared__ __align__(16) unsigned short x_lds[2][8192];         // 2 x 16384 B

  int bid = blockIdx.x;
  int wg  = (bid & 7) * (NWG / 8) + (bid >> 3);   // XCD-aware, bijective
  int nt  = wg / MT;
  int mt  = wg - nt * MT;

  int tid  = threadIdx.x;
  int lane = tid & 63;
  int wave = tid >> 6;          // 4 waves; wave-tile 112 x 64

  f32x4 acc[7][4];
#pragma unroll
  for (int i = 0; i < 7; ++i)
#pragma unroll
    for (int j = 0; j < 4; ++j)
      acc[i][j] = (f32x4){0.f, 0.f, 0.f, 0.f};

  // X staging ownership: thread -> (kb = wave -> 8 k-rows, 4 cols at lane*4)
  const float* xbase = X + (size_t)(nt * BN) + ((size_t)(wave * 8) << 16) + (lane << 2);
  int wslot0 = wave * 256 + (lane << 2);

  // fragment read addressing
  int a_rd    = (((lane >> 4) * BM) + (lane & 15)) * 16;            // + i*256
  int x_slot0 = (lane >> 4) * 256 + wave * 64 + (lane & 15);        // + jn*16

  const unsigned short* abase = A_ws + (size_t)mt * KSTEPS * ATILE_ELEMS;
  int a_st = wave * 512 + lane * 8;        // elem offset of this lane's DMA src
  int a_ld = wave * 512;                   // LDS elem base of this wave's chunk

  // ---- prologue: stage step 0 into buffer 0 ----
  {
    f32x4 v[8];
    const float* xs = xbase;               // ks=0: no K tail
#pragma unroll
    for (int dk = 0; dk < 8; ++dk) v[dk] = *(const f32x4*)(xs + ((size_t)dk << 16));
    const unsigned short* at = abase;      // ks=0
    async16(at + a_st, &a_lds[0][a_ld]);
    if (wave < 3) async16(at + a_st + 2048, &a_lds[0][a_ld + 2048]);
#pragma unroll
    for (int di = 0; di < 4; ++di) {
      u32x4 w;
      w.x = cvtpk(v[0][di], v[1][di]);
      w.y = cvtpk(v[2][di], v[3][di]);
      w.z = cvtpk(v[4][di], v[5][di]);
      w.w = cvtpk(v[6][di], v[7][di]);
      *(u32x4*)((char*)x_lds[0] + swz(wslot0 + di)) = w;
    }
  }
  __syncthreads();   // buffer 0 ready (vmcnt+lgkm drained by barrier semantics)

  // ---- main loop: compute buf[ks&1], stage ks+1 into buf[~ks&1] ----
  for (int ks = 0; ks < KSTEPS; ++ks) {
    int cur = ks & 1;
    bool more = (ks + 1 < KSTEPS);

    // (1) issue next step's global X loads first (consumed at (4);
    //     latency hides under (2)+(3))
    f32x4 v[8];
    if (more) {
      int ksn = ks + 1;
      int k0n = ksn * 32 + wave * 8;
      const float* xs = xbase + ((size_t)ksn << 21);
      if (k0n + 7 < KDIM) {
#pragma unroll
        for (int dk = 0; dk < 8; ++dk) v[dk] = *(const f32x4*)(xs + ((size_t)dk << 16));
      } else {     // wave-uniform tail branch (last step, wave 3)
#pragma unroll
        for (int dk = 0; dk < 8; ++dk)
          v[dk] = (k0n + dk < KDIM) ? *(const f32x4*)(xs + ((size_t)dk << 16))
                                    : (f32x4){0.f, 0.f, 0.f, 0.f};
      }
      // (2) A-DMA for ks+1 into the alternate buffer
      const unsigned short* at = abase + (ks + 1) * ATILE_ELEMS;
      async16(at + a_st, &a_lds[cur ^ 1][a_ld]);
      if (wave < 3) async16(at + a_st + 2048, &a_lds[cur ^ 1][a_ld + 2048]);
    }

    // (3) compute current buffer: 7 A-frags + 4 B-frags -> 28 MFMAs
    s16x8 af[7], xf[4];
#pragma unroll
    for (int i = 0; i < 7; ++i)
      af[i] = *(const s16x8*)((const char*)a_lds[cur] + a_rd + i * 256);
#pragma unroll
    for (int jn = 0; jn < 4; ++jn)
      xf[jn] = *(const s16x8*)((const char*)x_lds[cur] + swz(x_slot0 + jn * 16));
#pragma unroll
    for (int i = 0; i < 7; ++i)
#pragma unroll
      for (int jn = 0; jn < 4; ++jn)
        acc[i][jn] = __builtin_amdgcn_mfma_f32_16x16x32_bf16(af[i], xf[jn], acc[i][jn], 0, 0, 0);

    // (4) convert + swizzled ds_write of next X tile into alternate buffer
    if (more) {
#pragma unroll
      for (int di = 0; di < 4; ++di) {
        u32x4 w;
        w.x = cvtpk(v[0][di], v[1][di]);
        w.y = cvtpk(v[2][di], v[3][di]);
        w.z = cvtpk(v[4][di], v[5][di]);
        w.w = cvtpk(v[6][di], v[7][di]);
        *(u32x4*)((char*)x_lds[cur ^ 1] + swz(wslot0 + di)) = w;
      }
    }

    // one barrier per K-step: drains A-DMA (vmcnt) + ds_write (lgkm);
    // next iter reads buf^1, writes buf -> no other sync needed
    __syncthreads();
  }

  // ---- epilogue: + bias, relu, store ----
  int colbase = nt * BN + wave * 64 + (lane & 15);
#pragma unroll
  for (int i = 0; i < 7; ++i) {
    int r0 = mt * BM + i * 16 + ((lane >> 4) << 2);   // D row = (lane>>4)*4 + d
    f32x4 bv = *(const f32x4*)&Bias[r0];
#pragma unroll
    for (int jn = 0; jn < 4; ++jn) {
      size_t cb = ((size_t)r0 << 16) + (size_t)(colbase + jn * 16);
#pragma unroll
      for (int d = 0; d < 4; ++d) {
        float vv = acc[i][jn][d] + bv[d];
        C[cb + ((size_t)d << 16)] = fmaxf(vv, 0.0f);
      }
    }
  }
}

extern "C" void kernel_launch(void* const* d_in, const int* in_sizes, int n_in,
                              void* d_out, int out_size, void* d_ws, size_t ws_size,
                              hipStream_t stream) {
  const float* x  = (const float*)d_in[0];   // (28, 28, 65536) = [784][65536]
  const float* W  = (const float*)d_in[1];   // (28, 28, 28)
  const float* B  = (const float*)d_in[2];   // (28, 28, 1)
  float* out = (float*)d_out;
  unsigned short* A_ws = (unsigned short*)d_ws;  // 1.25 MB bf16 bcirc(W)

  build_A<<<(AWS_ELEMS + 255) / 256, 256, 0, stream>>>(W, A_ws);
  tnn_fused<<<NWG, 256, 0, stream>>>(x, A_ws, B, out);
}